// Round 2
// baseline (259.191 us; speedup 1.0000x reference)
//
#include <hip/hip_runtime.h>
#include <hip/hip_bf16.h>

typedef __attribute__((ext_vector_type(8))) short bf16x8;
typedef __attribute__((ext_vector_type(4))) float f32x4;
typedef unsigned short u16;

__device__ __forceinline__ u16 f2bf(float f) {
  __hip_bfloat16 h = __float2bfloat16(f);  // RNE
  u16 u;
  __builtin_memcpy(&u, &h, 2);
  return u;
}
__device__ __forceinline__ void cvt4_store(u16* dst, float4 v) {
  u16 rr[4] = {f2bf(v.x), f2bf(v.y), f2bf(v.z), f2bf(v.w)};
  uint2 p;
  __builtin_memcpy(&p, rr, 8);
  *(uint2*)dst = p;  // 8B-aligned by construction
}
__device__ __forceinline__ bf16x8 pack8(float4 a, float4 b) {
  u16 h[8] = {f2bf(a.x), f2bf(a.y), f2bf(a.z), f2bf(a.w),
              f2bf(b.x), f2bf(b.y), f2bf(b.z), f2bf(b.w)};
  bf16x8 r;
  __builtin_memcpy(&r, h, 16);
  return r;
}

// Dims: B=64, C=512, NE=80, NI=20, E=512. fp32 I/O, bf16 MFMA compute.
// Grid 512 (one block per column, no weight duplication), 512 threads.
// Waves: mw = wave&3 -> m-tile (16 batches); jh = wave>>2 ->
//   jh=0: e-col-tiles 0..2 ; jh=1: e-col-tiles 3..4 + i-col-tiles 0..1.
// Weights (in_proj/fb/w_ee/w_ei/w_ie) are loaded DIRECT from global as
// b-fragments (16 rows x 128B per wave-instr); the 4 m-tile waves re-read
// the same slice -> L1 filters, HBM sees each weight once. LDS holds only
// the A-side (thal+inc sum, l23/re/ri), double/2-deep prefetched.
// MFMA 16x16x32 layout: a A[m=lane&15][k=quad*8+j], b Bt[n=lane&15][k=...],
// C/D C[m=quad*4+reg][n=lane&15] (m89/m91).
// launch_bounds(512,4): 16 waves/CU (2 blocks), VGPR cap 128.

__global__ __launch_bounds__(512, 4) void ei_cols_mfma(
    const float* __restrict__ thal,     // [64][512]
    const float* __restrict__ inc,      // [64][512][512]
    const float* __restrict__ l23,      // [64][512][80]
    const float* __restrict__ re_in,    // [64][512][80]
    const float* __restrict__ ri_in,    // [64][512][20]
    const float* __restrict__ ev_in,    // [64][512][80]
    const float* __restrict__ iv_in,    // [64][512][20]
    const float* __restrict__ in_proj,  // [512][80][512]
    const float* __restrict__ fb_proj,  // [512][80][80]
    const float* __restrict__ w_ee,     // [512][80][80]
    const float* __restrict__ w_ei,     // [512][20][80]
    const float* __restrict__ w_ie,     // [512][80][20]
    float* __restrict__ out)            // r_e|r_i|v_e|v_i flat fp32
{
  // LDS map: [0,9216) = A buf0, [9216,18432) = A buf1 (bf16 [64][72]),
  //          [18432, 31744) = As/Ri region for phases B/C/D.
  __shared__ __align__(16) unsigned char smem[31744];
  const int c = blockIdx.x;
  const int tid = threadIdx.x;
  const int lane = tid & 63;
  const int wave = tid >> 6;
  const int nidx = lane & 15;
  const int quad = lane >> 4;
  const int mw = wave & 3;
  const int jh = wave >> 2;
  const int m0 = mw * 16;

  f32x4 acc_e[3], acc_i[2];
#pragma unroll
  for (int j = 0; j < 3; ++j) acc_e[j] = (f32x4){0.f, 0.f, 0.f, 0.f};
#pragma unroll
  for (int j = 0; j < 2; ++j) acc_i[j] = (f32x4){0.f, 0.f, 0.f, 0.f};

  const float* wA = in_proj + (size_t)c * 40960;

  // ---- Phase A: I_ext = (thal+inc).in_proj^T, K=512 ----------------------
  // A-side (thal+inc): 2-deep register pipeline -> bf16 LDS double buffer.
  // W-side: direct-from-global b-frags (L1-filtered across the 4 m-waves).
  float4 tv0[2], gv0[2], tv1[2], gv1[2];
  float4 fbv[3];  // l23 prefetch, loaded at iter 5

  auto loadA = [&](float4* tv, float4* gv, int k0) {
#pragma unroll
    for (int j = 0; j < 2; ++j) {
      int l = tid + j * 512;
      int b = l >> 4, kk = (l & 15) << 2;
      tv[j] = *(const float4*)(thal + b * 512 + k0 + kk);
      gv[j] = *(const float4*)(inc + (size_t)b * 262144 + (size_t)c * 512 + k0 + kk);
    }
  };
  auto storeA = [&](int p, float4* tv, float4* gv) {
    u16* A = (u16*)(smem + p * 9216);
#pragma unroll
    for (int j = 0; j < 2; ++j) {
      int l = tid + j * 512;
      int b = l >> 4, kk = (l & 15) << 2;
      float4 s;
      s.x = tv[j].x + gv[j].x; s.y = tv[j].y + gv[j].y;
      s.z = tv[j].z + gv[j].z; s.w = tv[j].w + gv[j].w;
      cvt4_store(A + b * 72 + kk, s);
    }
  };

  loadA(tv0, gv0, 0);
  storeA(0, tv0, gv0);      // cold stall (once)
  loadA(tv1, gv1, 64);      // step 1 in flight
  loadA(tv0, gv0, 128);     // step 2 in flight

  for (int i = 0; i < 8; ++i) {
    __syncthreads();  // buf[i&1] (step i) ready for all waves
    const int p1 = (i + 1) & 1;
    if (i < 7) {      // store step i+1 (its loads have been in flight >=1 iter)
      if (p1) storeA(1, tv1, gv1); else storeA(0, tv0, gv0);
    }
    if (i < 5) {      // issue step i+3 into the set just consumed
      if (p1) loadA(tv1, gv1, (i + 3) * 64); else loadA(tv0, gv0, (i + 3) * 64);
    }
    if (i == 5) {     // prefetch l23 for phase B
#pragma unroll
      for (int j = 0; j < 3; ++j) {
        int l = tid + j * 512;
        if (l < 1280) {
          int b = l / 20, kk = (l % 20) << 2;
          fbv[j] = *(const float4*)(l23 + ((size_t)b * 512 + c) * 80 + kk);
        }
      }
    }
    if (i == 7) {     // store l23 -> As region (disjoint from A bufs)
      u16* As = (u16*)(smem + 18432);
#pragma unroll
      for (int j = 0; j < 3; ++j) {
        int l = tid + j * 512;
        if (l < 1280) {
          int b = l / 20, kk = (l % 20) << 2;
          cvt4_store(As + b * 104 + kk, fbv[j]);
        }
      }
      if (tid < 128) {
        int b = tid >> 1, off = 80 + (tid & 1) * 8;
        *(uint4*)(As + b * 104 + off) = (uint4){0u, 0u, 0u, 0u};
      }
    }
    // compute step i
    const u16* A = (const u16*)(smem + (i & 1) * 9216);
    const float* wb = wA + i * 64;
#pragma unroll
    for (int kk0 = 0; kk0 < 64; kk0 += 32) {
      bf16x8 a = *(const bf16x8*)(A + (m0 + nidx) * 72 + kk0 + quad * 8);
      if (jh == 0) {
#pragma unroll
        for (int j = 0; j < 3; ++j) {
          const float* p = wb + (size_t)(j * 16 + nidx) * 512 + kk0 + quad * 8;
          bf16x8 b = pack8(*(const float4*)p, *(const float4*)(p + 4));
          acc_e[j] = __builtin_amdgcn_mfma_f32_16x16x32_bf16(a, b, acc_e[j], 0, 0, 0);
        }
      } else {
#pragma unroll
        for (int j = 0; j < 2; ++j) {
          const float* p = wb + (size_t)((3 + j) * 16 + nidx) * 512 + kk0 + quad * 8;
          bf16x8 b = pack8(*(const float4*)p, *(const float4*)(p + 4));
          acc_e[j] = __builtin_amdgcn_mfma_f32_16x16x32_bf16(a, b, acc_e[j], 0, 0, 0);
        }
      }
    }
  }

  // ---- Phase B: I_fb = l23 . fb_proj^T, K=80 (tail-masked) ---------------
  float4 rev[3];  // re prefetch for phase C (hides under B k-loop)
#pragma unroll
  for (int j = 0; j < 3; ++j) {
    int l = tid + j * 512;
    if (l < 1280) {
      int b = l / 20, kk = (l % 20) << 2;
      rev[j] = *(const float4*)(re_in + ((size_t)b * 512 + c) * 80 + kk);
    }
  }
  __syncthreads();  // As(l23) ready
  {
    const u16* As = (const u16*)(smem + 18432);
    const float* fb = fb_proj + (size_t)c * 6400;
#pragma unroll
    for (int kk0 = 0; kk0 < 96; kk0 += 32) {
      bf16x8 a = *(const bf16x8*)(As + (m0 + nidx) * 104 + kk0 + quad * 8);
      const bool full = (kk0 < 64) || (quad < 2);
      if (jh == 0) {
#pragma unroll
        for (int j = 0; j < 3; ++j) {
          const float* p = fb + (size_t)(j * 16 + nidx) * 80 + kk0 + quad * 8;
          float4 w0 = {0.f, 0.f, 0.f, 0.f}, w1 = {0.f, 0.f, 0.f, 0.f};
          if (full) { w0 = *(const float4*)p; w1 = *(const float4*)(p + 4); }
          bf16x8 b = pack8(w0, w1);
          acc_e[j] = __builtin_amdgcn_mfma_f32_16x16x32_bf16(a, b, acc_e[j], 0, 0, 0);
        }
      } else {
#pragma unroll
        for (int j = 0; j < 2; ++j) {
          const float* p = fb + (size_t)((3 + j) * 16 + nidx) * 80 + kk0 + quad * 8;
          float4 w0 = {0.f, 0.f, 0.f, 0.f}, w1 = {0.f, 0.f, 0.f, 0.f};
          if (full) { w0 = *(const float4*)p; w1 = *(const float4*)(p + 4); }
          bf16x8 b = pack8(w0, w1);
          acc_e[j] = __builtin_amdgcn_mfma_f32_16x16x32_bf16(a, b, acc_e[j], 0, 0, 0);
        }
      }
    }
  }

  // ---- Phase C: I_ee = r_e.W_ee^T ; I_ei = r_e.W_ei^T --------------------
  __syncthreads();  // all waves done reading As(l23)
  {
    u16* Asw = (u16*)(smem + 18432);
#pragma unroll
    for (int j = 0; j < 3; ++j) {
      int l = tid + j * 512;
      if (l < 1280) {
        int b = l / 20, kk = (l % 20) << 2;
        cvt4_store(Asw + b * 104 + kk, rev[j]);
      }
    }
    if (tid < 128) {
      int b = tid >> 1, off = 80 + (tid & 1) * 8;
      *(uint4*)(Asw + b * 104 + off) = (uint4){0u, 0u, 0u, 0u};
    }
  }
  float4 riv;  // ri prefetch for phase D (hides under C k-loop)
  if (tid < 320) {
    int b = tid / 5, kk = (tid % 5) << 2;
    riv = *(const float4*)(ri_in + ((size_t)b * 512 + c) * 20 + kk);
  }
  __syncthreads();  // As(re) ready
  {
    const u16* As = (const u16*)(smem + 18432);
    const float* wee = w_ee + (size_t)c * 6400;
    const float* wei = w_ei + (size_t)c * 1600;
#pragma unroll
    for (int kk0 = 0; kk0 < 96; kk0 += 32) {
      bf16x8 a = *(const bf16x8*)(As + (m0 + nidx) * 104 + kk0 + quad * 8);
      const bool full = (kk0 < 64) || (quad < 2);
      if (jh == 0) {
#pragma unroll
        for (int j = 0; j < 3; ++j) {
          const float* p = wee + (size_t)(j * 16 + nidx) * 80 + kk0 + quad * 8;
          float4 w0 = {0.f, 0.f, 0.f, 0.f}, w1 = {0.f, 0.f, 0.f, 0.f};
          if (full) { w0 = *(const float4*)p; w1 = *(const float4*)(p + 4); }
          bf16x8 b = pack8(w0, w1);
          acc_e[j] = __builtin_amdgcn_mfma_f32_16x16x32_bf16(a, b, acc_e[j], 0, 0, 0);
        }
      } else {
#pragma unroll
        for (int j = 0; j < 2; ++j) {
          const float* p = wee + (size_t)((3 + j) * 16 + nidx) * 80 + kk0 + quad * 8;
          float4 w0 = {0.f, 0.f, 0.f, 0.f}, w1 = {0.f, 0.f, 0.f, 0.f};
          if (full) { w0 = *(const float4*)p; w1 = *(const float4*)(p + 4); }
          bf16x8 b = pack8(w0, w1);
          acc_e[j] = __builtin_amdgcn_mfma_f32_16x16x32_bf16(a, b, acc_e[j], 0, 0, 0);
        }
#pragma unroll
        for (int j = 0; j < 2; ++j) {
          int row = j * 16 + nidx;
          float4 w0 = {0.f, 0.f, 0.f, 0.f}, w1 = {0.f, 0.f, 0.f, 0.f};
          if (row < 20 && full) {
            const float* p = wei + (size_t)row * 80 + kk0 + quad * 8;
            w0 = *(const float4*)p; w1 = *(const float4*)(p + 4);
          }
          bf16x8 b = pack8(w0, w1);
          acc_i[j] = __builtin_amdgcn_mfma_f32_16x16x32_bf16(a, b, acc_i[j], 0, 0, 0);
        }
      }
    }
  }

  // ---- Phase D: I_ie = r_i . (-W_ie)^T, K=20 (pad 32) --------------------
  __syncthreads();  // all waves done reading As(re)
  {
    u16* Ri = (u16*)(smem + 18432);
    if (tid < 320) {
      int b = tid / 5, kk = (tid % 5) << 2;
      cvt4_store(Ri + b * 40 + kk, riv);
    }
    if (tid < 192) {
      int b = tid / 3, kk = 20 + (tid % 3) * 4;
      *(uint2*)(Ri + b * 40 + kk) = (uint2){0u, 0u};
    }
  }
  // Epilogue state loads: latency hides under barrier drain + D MFMA.
  float evr[3][4], ivr[2][4];
  const int row0 = m0 + quad * 4;
  if (jh == 0) {
#pragma unroll
    for (int j = 0; j < 3; ++j) {
      int col = j * 16 + nidx;
#pragma unroll
      for (int r = 0; r < 4; ++r)
        evr[j][r] = ev_in[((size_t)(row0 + r) * 512 + c) * 80 + col];
    }
  } else {
#pragma unroll
    for (int j = 0; j < 2; ++j) {
      int col = 48 + j * 16 + nidx;
#pragma unroll
      for (int r = 0; r < 4; ++r)
        evr[j][r] = ev_in[((size_t)(row0 + r) * 512 + c) * 80 + col];
    }
#pragma unroll
    for (int j = 0; j < 2; ++j) {
      int col = j * 16 + nidx;
#pragma unroll
      for (int r = 0; r < 4; ++r)
        ivr[j][r] = (col < 20)
            ? iv_in[((size_t)(row0 + r) * 512 + c) * 20 + col] : 0.f;
    }
  }
  __syncthreads();  // Ri ready
  {
    const u16* Ri = (const u16*)(smem + 18432);
    bf16x8 a = *(const bf16x8*)(Ri + (m0 + nidx) * 40 + quad * 8);
    auto wieF = [&](int row) -> bf16x8 {
      const float* p = w_ie + (size_t)c * 1600 + row * 20 + quad * 8;
      float4 w0 = {0.f, 0.f, 0.f, 0.f}, w1 = {0.f, 0.f, 0.f, 0.f};
      if (quad < 2) { w0 = *(const float4*)p; w1 = *(const float4*)(p + 4); }
      else if (quad == 2) { w0 = *(const float4*)p; }
      w0.x = -w0.x; w0.y = -w0.y; w0.z = -w0.z; w0.w = -w0.w;
      w1.x = -w1.x; w1.y = -w1.y; w1.z = -w1.z; w1.w = -w1.w;
      return pack8(w0, w1);
    };
    if (jh == 0) {
#pragma unroll
      for (int j = 0; j < 3; ++j) {
        bf16x8 b = wieF(j * 16 + nidx);
        acc_e[j] = __builtin_amdgcn_mfma_f32_16x16x32_bf16(a, b, acc_e[j], 0, 0, 0);
      }
    } else {
#pragma unroll
      for (int j = 0; j < 2; ++j) {
        bf16x8 b = wieF((3 + j) * 16 + nidx);
        acc_e[j] = __builtin_amdgcn_mfma_f32_16x16x32_bf16(a, b, acc_e[j], 0, 0, 0);
      }
    }
  }

  // ---- Epilogue: v = v_old + 0.1*(I - v_old) ; r = relu(v), direct -------
  {
    const size_t R_ri = 2621440u;
    const size_t R_ve = 3276800u;
    const size_t R_vi = 5898240u;
    if (jh == 0) {
#pragma unroll
      for (int j = 0; j < 3; ++j) {
        int col = j * 16 + nidx;
#pragma unroll
        for (int r = 0; r < 4; ++r) {
          size_t g = ((size_t)(row0 + r) * 512 + c) * 80 + col;
          float e0 = evr[j][r];
          float v = e0 + 0.1f * (acc_e[j][r] - e0);
          out[g] = fmaxf(v, 0.f);
          out[R_ve + g] = v;
        }
      }
    } else {
#pragma unroll
      for (int j = 0; j < 2; ++j) {
        int col = 48 + j * 16 + nidx;
#pragma unroll
        for (int r = 0; r < 4; ++r) {
          size_t g = ((size_t)(row0 + r) * 512 + c) * 80 + col;
          float e0 = evr[j][r];
          float v = e0 + 0.1f * (acc_e[j][r] - e0);
          out[g] = fmaxf(v, 0.f);
          out[R_ve + g] = v;
        }
      }
#pragma unroll
      for (int j = 0; j < 2; ++j) {
        int col = j * 16 + nidx;
        if (col < 20) {
#pragma unroll
          for (int r = 0; r < 4; ++r) {
            size_t g = ((size_t)(row0 + r) * 512 + c) * 20 + col;
            float i0 = ivr[j][r];
            float v = i0 + 0.1f * (acc_i[j][r] - i0);
            out[R_ri + g] = fmaxf(v, 0.f);
            out[R_vi + g] = v;
          }
        }
      }
    }
  }
}

extern "C" void kernel_launch(void* const* d_in, const int* in_sizes, int n_in,
                              void* d_out, int out_size, void* d_ws, size_t ws_size,
                              hipStream_t stream) {
  const float* thal = (const float*)d_in[0];
  const float* inc = (const float*)d_in[1];
  const float* l23 = (const float*)d_in[2];
  const float* re = (const float*)d_in[3];
  const float* ri = (const float*)d_in[4];
  const float* ev = (const float*)d_in[5];
  const float* iv = (const float*)d_in[6];
  const float* in_proj = (const float*)d_in[7];
  const float* fb_proj = (const float*)d_in[8];
  const float* w_ee = (const float*)d_in[9];
  const float* w_ei = (const float*)d_in[10];
  const float* w_ie = (const float*)d_in[11];
  float* out = (float*)d_out;
  ei_cols_mfma<<<dim3(512), dim3(512), 0, stream>>>(
      thal, inc, l23, re, ri, ev, iv, in_proj, fb_proj, w_ee, w_ei, w_ie, out);
}